// Round 2
// baseline (622.497 us; speedup 1.0000x reference)
//
#include <hip/hip_runtime.h>
#include <stdint.h>

#define IN_F   8192
#define OUT_F  8192
#define BATCH  1024
#define BT     4              // batch rows staged in LDS per workgroup
#define NBT    (BATCH / BT)   // 256 batch tiles
#define COL_HALVES 2
#define COLS_PER_WG (OUT_F / COL_HALVES)  // 4096
#define MAIN_THREADS 256

__device__ __forceinline__ unsigned f32_to_bf16_bits_rne(float f) {
    union { float f; unsigned u; } v; v.f = f;
    unsigned u = v.u;
    unsigned r = u + 0x7FFFu + ((u >> 16) & 1u);
    return r >> 16;   // low 16 bits hold the bf16 pattern
}
__device__ __forceinline__ float bf16_lo_bits_to_f32(unsigned b) {
    union { unsigned u; float f; } v; v.u = b << 16; return v.f;
}
__device__ __forceinline__ float bf16_hi_bits_to_f32(unsigned b) {
    union { unsigned u; float f; } v; v.u = b & 0xFFFF0000u; return v.f;
}

__global__ void zero_kernel(int* __restrict__ p, int n) {
    int i = blockIdx.x * blockDim.x + threadIdx.x;
    if (i < n) p[i] = 0;
}

__global__ void count_kernel(const int* __restrict__ cols, int* __restrict__ counts, int nnz) {
    int i = blockIdx.x * blockDim.x + threadIdx.x;
    if (i < nnz) atomicAdd(&counts[cols[i]], 1);
}

// Exclusive scan of counts[8192] -> starts[8193]; also seeds cursor = starts.
__global__ __launch_bounds__(1024) void scan_kernel(const int* __restrict__ counts,
                                                    int* __restrict__ starts,
                                                    int* __restrict__ cursor) {
    __shared__ int lds[1024];
    int t = threadIdx.x;
    int local[8];
    int sum = 0;
#pragma unroll
    for (int i = 0; i < 8; ++i) { local[i] = sum; sum += counts[t * 8 + i]; }
    lds[t] = sum;
    __syncthreads();
    for (int off = 1; off < 1024; off <<= 1) {
        int v = (t >= off) ? lds[t - off] : 0;
        __syncthreads();
        lds[t] += v;
        __syncthreads();
    }
    int base = (t > 0) ? lds[t - 1] : 0;
#pragma unroll
    for (int i = 0; i < 8; ++i) {
        int s = base + local[i];
        starts[t * 8 + i] = s;
        cursor[t * 8 + i] = s;
    }
    if (t == 1023) starts[OUT_F] = lds[1023];
}

// Pack each nnz into one dword: (bf16(value) bits << 16) | row  (row < 8192 fits u16).
// Inputs are bf16-valued f32, so the bf16 rounding is exact.
__global__ void scatter_kernel(const int* __restrict__ rows, const int* __restrict__ cols,
                               const float* __restrict__ vals,
                               int* __restrict__ cursor, unsigned* __restrict__ csc, int nnz) {
    int i = blockIdx.x * blockDim.x + threadIdx.x;
    if (i < nnz) {
        int c = cols[i];
        unsigned vb = f32_to_bf16_bits_rne(vals[i]);
        unsigned pk = (vb << 16) | (unsigned)rows[i];
        int pos = atomicAdd(&cursor[c], 1);
        csc[pos] = pk;
    }
}

// Main SpMM: one WG = (batch tile of 4) x (half of the 8192 columns).
// LDS holds x[b0..b0+3, :] as 4 packed bf16 per input row (64 KB -> 2 WGs/CU).
__global__ __launch_bounds__(MAIN_THREADS) void spmm_kernel(
        const float* __restrict__ x,
        const float* __restrict__ bias,
        const int* __restrict__ starts,
        const unsigned* __restrict__ csc,
        float* __restrict__ out) {
    __shared__ unsigned long long xl[IN_F];  // 64 KB
    int w = blockIdx.x;
    int bt = w >> 1;
    int half = w & 1;
    int t = threadIdx.x;
    int b0 = bt * BT;

    // Stage x tile: 4 coalesced f32 row-streams -> packed bf16x4 (8B) per input row.
    for (int r = t; r < IN_F; r += MAIN_THREADS) {
        unsigned u0 = f32_to_bf16_bits_rne(x[(b0 + 0) * IN_F + r]);
        unsigned u1 = f32_to_bf16_bits_rne(x[(b0 + 1) * IN_F + r]);
        unsigned u2 = f32_to_bf16_bits_rne(x[(b0 + 2) * IN_F + r]);
        unsigned u3 = f32_to_bf16_bits_rne(x[(b0 + 3) * IN_F + r]);
        unsigned lo = (u1 << 16) | u0;
        unsigned hi = (u3 << 16) | u2;
        xl[r] = ((unsigned long long)hi << 32) | lo;
    }
    __syncthreads();

#pragma unroll 1
    for (int it = 0; it < COLS_PER_WG / MAIN_THREADS; ++it) {
        int col = half * COLS_PER_WG + it * MAIN_THREADS + t;
        int p0 = starts[col];
        int p1 = starts[col + 1];
        float a0 = 0.f, a1 = 0.f, a2 = 0.f, a3 = 0.f;
        for (int p = p0; p < p1; ++p) {
            unsigned pk = csc[p];
            float val = bf16_hi_bits_to_f32(pk);     // value bits already in high half
            int row = pk & 0xFFFFu;
            unsigned long long d = xl[row];
            unsigned lo = (unsigned)d;
            unsigned hi = (unsigned)(d >> 32);
            a0 += val * bf16_lo_bits_to_f32(lo);
            a1 += val * bf16_hi_bits_to_f32(lo);
            a2 += val * bf16_lo_bits_to_f32(hi);
            a3 += val * bf16_hi_bits_to_f32(hi);
        }
        float bv = bias[col];
        out[(size_t)(b0 + 0) * OUT_F + col] = a0 + bv;
        out[(size_t)(b0 + 1) * OUT_F + col] = a1 + bv;
        out[(size_t)(b0 + 2) * OUT_F + col] = a2 + bv;
        out[(size_t)(b0 + 3) * OUT_F + col] = a3 + bv;
    }
}

extern "C" void kernel_launch(void* const* d_in, const int* in_sizes, int n_in,
                              void* d_out, int out_size, void* d_ws, size_t ws_size,
                              hipStream_t stream) {
    const float* x      = (const float*)d_in[0];
    const float* values = (const float*)d_in[1];
    const float* bias   = (const float*)d_in[2];
    const int* rows = (const int*)d_in[3];
    const int* cols = (const int*)d_in[4];
    float* out = (float*)d_out;
    int nnz = in_sizes[1];

    // Workspace layout (all 4-byte aligned): counts | starts | cursor | csc
    int* counts = (int*)d_ws;                     // 8192
    int* starts = counts + OUT_F;                 // 8193
    int* cursor = starts + OUT_F + 1;             // 8192
    unsigned* csc = (unsigned*)(cursor + OUT_F);  // nnz dwords

    zero_kernel<<<(OUT_F + 255) / 256, 256, 0, stream>>>(counts, OUT_F);
    count_kernel<<<(nnz + 255) / 256, 256, 0, stream>>>(cols, counts, nnz);
    scan_kernel<<<1, 1024, 0, stream>>>(counts, starts, cursor);
    scatter_kernel<<<(nnz + 255) / 256, 256, 0, stream>>>(rows, cols, values, cursor, csc, nnz);
    spmm_kernel<<<NBT * COL_HALVES, MAIN_THREADS, 0, stream>>>(x, bias, starts, csc, out);
}

// Round 3
// 317.723 us; speedup vs baseline: 1.9592x; 1.9592x over previous
//
#include <hip/hip_runtime.h>
#include <stdint.h>

#define IN_F   8192
#define OUT_F  8192
#define BATCH  1024
#define BT     4              // batch rows staged in LDS per workgroup
#define NBT    (BATCH / BT)   // 256 batch tiles
#define COL_HALVES 2
#define MAIN_THREADS 256
#define NGROUPS (OUT_F / 64)  // 128 groups of 64 columns (one wave each)

// workspace dword offsets
#define WS_COUNTS 0            // 8192
#define WS_CURSOR 8192         // 8192
#define WS_GOFF   16384        // 129
#define WS_ELL    16896        // 256-dword aligned; ELL entries
#define ELL_ZERO_CAP 2097152   // zero up to 8 MB of ELL region (actual ~0.92M dwords)

__device__ __forceinline__ unsigned f32_to_bf16_bits_rne(float f) {
    union { float f; unsigned u; } v; v.f = f;
    unsigned u = v.u;
    unsigned r = u + 0x7FFFu + ((u >> 16) & 1u);
    return r >> 16;
}
__device__ __forceinline__ float bf16_lo_bits_to_f32(unsigned b) {
    union { unsigned u; float f; } v; v.u = b << 16; return v.f;
}
__device__ __forceinline__ float bf16_hi_bits_to_f32(unsigned b) {
    union { unsigned u; float f; } v; v.u = b & 0xFFFF0000u; return v.f;
}

__global__ void zero_kernel(int* __restrict__ p, int n) {
    int i = blockIdx.x * blockDim.x + threadIdx.x;
    if (i < n) p[i] = 0;
}

__global__ void zero4_kernel(uint4* __restrict__ p, int n4) {
    int i = blockIdx.x * blockDim.x + threadIdx.x;
    if (i < n4) p[i] = make_uint4(0, 0, 0, 0);
}

__global__ void count_kernel(const int* __restrict__ cols, int* __restrict__ counts, int nnz) {
    int i = blockIdx.x * blockDim.x + threadIdx.x;
    if (i < nnz) atomicAdd(&counts[cols[i]], 1);
}

// Per 64-column group: L_g = roundup4(max count) ; exclusive scan (scaled by 64 dwords/slot) -> goff
__global__ __launch_bounds__(128) void group_kernel(const int* __restrict__ counts,
                                                    int* __restrict__ goff) {
    __shared__ int lds[128];
    int g = threadIdx.x;
    int m = 0;
#pragma unroll 8
    for (int i = 0; i < 64; ++i) m = max(m, counts[g * 64 + i]);
    int L = (m + 3) & ~3;            // slots per column, multiple of 4
    int sz = L * 64;                 // dwords for this group (multiple of 256)
    lds[g] = sz;
    __syncthreads();
    for (int off = 1; off < 128; off <<= 1) {
        int v = (g >= off) ? lds[g - off] : 0;
        __syncthreads();
        lds[g] += v;
        __syncthreads();
    }
    goff[g] = lds[g] - sz;           // exclusive
    if (g == 127) goff[128] = lds[127];
}

// Scatter nnz into ELL: entry dword = (bf16(val) bits << 16) | row.
// index = goff[g] + (s>>2)*256 + lane*4 + (s&3), s = per-column cursor.
__global__ void scatter_kernel(const int* __restrict__ rows, const int* __restrict__ cols,
                               const float* __restrict__ vals,
                               int* __restrict__ cursor, const int* __restrict__ goff,
                               unsigned* __restrict__ ell, int nnz) {
    int i = blockIdx.x * blockDim.x + threadIdx.x;
    if (i < nnz) {
        int c = cols[i];
        int g = c >> 6, lane = c & 63;
        unsigned vb = f32_to_bf16_bits_rne(vals[i]);
        unsigned pk = (vb << 16) | (unsigned)rows[i];
        int s = atomicAdd(&cursor[c], 1);
        int idx = goff[g] + ((s >> 2) << 8) + (lane << 2) + (s & 3);
        ell[idx] = pk;
    }
}

// Main SpMM: WG = (batch tile of 4) x (half the columns). Each wave owns 16
// 64-column groups; lane l <-> column g*64+l. ELL gives coalesced uint4
// loads (4 entries/lane/load), wave-uniform trip counts, 4-deep LDS ILP.
__global__ __launch_bounds__(MAIN_THREADS) void spmm_kernel(
        const float* __restrict__ x,
        const float* __restrict__ bias,
        const int* __restrict__ goff,
        const unsigned* __restrict__ ell,
        float* __restrict__ out) {
    __shared__ unsigned long long xl[IN_F];  // 64 KB -> 2 WGs/CU
    int w = blockIdx.x;
    int bt = w >> 1;
    int half = w & 1;
    int t = threadIdx.x;
    int b0 = bt * BT;

    for (int r = t; r < IN_F; r += MAIN_THREADS) {
        unsigned u0 = f32_to_bf16_bits_rne(x[(b0 + 0) * IN_F + r]);
        unsigned u1 = f32_to_bf16_bits_rne(x[(b0 + 1) * IN_F + r]);
        unsigned u2 = f32_to_bf16_bits_rne(x[(b0 + 2) * IN_F + r]);
        unsigned u3 = f32_to_bf16_bits_rne(x[(b0 + 3) * IN_F + r]);
        unsigned lo = (u1 << 16) | u0;
        unsigned hi = (u3 << 16) | u2;
        xl[r] = ((unsigned long long)hi << 32) | lo;
    }
    __syncthreads();

    int wave = t >> 6;
    int lane = t & 63;

#pragma unroll 1
    for (int it = 0; it < 16; ++it) {
        int g = half * 64 + wave * 16 + it;
        int base = goff[g];
        int n4 = (goff[g + 1] - base) >> 8;       // uint4 iterations (= L_g/4)
        const uint4* ep = (const uint4*)(ell + base);
        int col = (g << 6) + lane;
        float a0 = 0.f, a1 = 0.f, a2 = 0.f, a3 = 0.f;
#pragma unroll 1
        for (int s4 = 0; s4 < n4; ++s4) {
            uint4 q = ep[s4 * 64 + lane];
#pragma unroll
            for (int e = 0; e < 4; ++e) {
                unsigned pk = (e == 0) ? q.x : (e == 1) ? q.y : (e == 2) ? q.z : q.w;
                float val = bf16_hi_bits_to_f32(pk);
                int row = pk & 0xFFFFu;
                unsigned long long d = xl[row];
                unsigned lo = (unsigned)d;
                unsigned hi = (unsigned)(d >> 32);
                a0 += val * bf16_lo_bits_to_f32(lo);
                a1 += val * bf16_hi_bits_to_f32(lo);
                a2 += val * bf16_lo_bits_to_f32(hi);
                a3 += val * bf16_hi_bits_to_f32(hi);
            }
        }
        float bv = bias[col];
        out[(size_t)(b0 + 0) * OUT_F + col] = a0 + bv;
        out[(size_t)(b0 + 1) * OUT_F + col] = a1 + bv;
        out[(size_t)(b0 + 2) * OUT_F + col] = a2 + bv;
        out[(size_t)(b0 + 3) * OUT_F + col] = a3 + bv;
    }
}

extern "C" void kernel_launch(void* const* d_in, const int* in_sizes, int n_in,
                              void* d_out, int out_size, void* d_ws, size_t ws_size,
                              hipStream_t stream) {
    const float* x      = (const float*)d_in[0];
    const float* values = (const float*)d_in[1];
    const float* bias   = (const float*)d_in[2];
    const int* rows = (const int*)d_in[3];
    const int* cols = (const int*)d_in[4];
    float* out = (float*)d_out;
    int nnz = in_sizes[1];

    int* wsi = (int*)d_ws;
    int* counts = wsi + WS_COUNTS;
    int* cursor = wsi + WS_CURSOR;
    int* goff   = wsi + WS_GOFF;
    unsigned* ell = (unsigned*)(wsi + WS_ELL);

    long long avail = (long long)(ws_size / 4) - WS_ELL;
    int zero_dw = (int)((avail < ELL_ZERO_CAP) ? (avail < 0 ? 0 : avail) : ELL_ZERO_CAP);
    int zero_n4 = zero_dw >> 2;

    zero_kernel<<<(16384 + 255) / 256, 256, 0, stream>>>(counts, 16384);  // counts+cursor
    count_kernel<<<(nnz + 255) / 256, 256, 0, stream>>>(cols, counts, nnz);
    group_kernel<<<1, 128, 0, stream>>>(counts, goff);
    zero4_kernel<<<(zero_n4 + 255) / 256, 256, 0, stream>>>((uint4*)ell, zero_n4);
    scatter_kernel<<<(nnz + 255) / 256, 256, 0, stream>>>(rows, cols, values, cursor, goff, ell, nnz);
    spmm_kernel<<<NBT * COL_HALVES, MAIN_THREADS, 0, stream>>>(x, bias, goff, ell, out);
}

// Round 4
// 222.751 us; speedup vs baseline: 2.7946x; 1.4264x over previous
//
#include <hip/hip_runtime.h>
#include <stdint.h>

#define IN_F   8192
#define OUT_F  8192
#define BATCH  1024
#define BT     4              // batch rows staged in LDS per workgroup
#define NBT    (BATCH / BT)   // 256 batch tiles
#define COL_HALVES 2
#define MAIN_THREADS 512      // 8 waves -> with 64KB LDS: 2 WG/CU = 16 waves/CU
#define GROUPS_PER_WAVE 8     // 8 waves x 8 groups = 64 groups = half the columns

// workspace dword offsets
#define WS_COUNTS 0            // 8192
#define WS_CURSOR 8192         // 8192
#define WS_GOFF   16384        // 129
#define WS_ELL    16896        // 256-dword aligned; ELL entries
#define ELL_ZERO_CAP 2097152   // zero up to 8 MB of ELL region (actual ~0.92M dwords)

__device__ __forceinline__ unsigned f32_to_bf16_bits_rne(float f) {
    union { float f; unsigned u; } v; v.f = f;
    unsigned u = v.u;
    unsigned r = u + 0x7FFFu + ((u >> 16) & 1u);
    return r >> 16;
}
__device__ __forceinline__ float bf16_lo_bits_to_f32(unsigned b) {
    union { unsigned u; float f; } v; v.u = b << 16; return v.f;
}
__device__ __forceinline__ float bf16_hi_bits_to_f32(unsigned b) {
    union { unsigned u; float f; } v; v.u = b & 0xFFFF0000u; return v.f;
}

__global__ void zero_kernel(int* __restrict__ p, int n) {
    int i = blockIdx.x * blockDim.x + threadIdx.x;
    if (i < n) p[i] = 0;
}

__global__ void zero4_kernel(uint4* __restrict__ p, int n4) {
    int i = blockIdx.x * blockDim.x + threadIdx.x;
    if (i < n4) p[i] = make_uint4(0, 0, 0, 0);
}

__global__ void count_kernel(const int* __restrict__ cols, int* __restrict__ counts, int nnz) {
    int i = blockIdx.x * blockDim.x + threadIdx.x;
    if (i < nnz) atomicAdd(&counts[cols[i]], 1);
}

// Per 64-column group: L_g = roundup4(max count); exclusive scan of group sizes -> goff
__global__ __launch_bounds__(128) void group_kernel(const int* __restrict__ counts,
                                                    int* __restrict__ goff) {
    __shared__ int lds[128];
    int g = threadIdx.x;
    int m = 0;
#pragma unroll 8
    for (int i = 0; i < 64; ++i) m = max(m, counts[g * 64 + i]);
    int L = (m + 3) & ~3;            // slots per column, multiple of 4
    int sz = L * 64;                 // dwords for this group (multiple of 256)
    lds[g] = sz;
    __syncthreads();
    for (int off = 1; off < 128; off <<= 1) {
        int v = (g >= off) ? lds[g - off] : 0;
        __syncthreads();
        lds[g] += v;
        __syncthreads();
    }
    goff[g] = lds[g] - sz;           // exclusive
    if (g == 127) goff[128] = lds[127];
}

// Scatter nnz into ELL: entry dword = (bf16(val) bits << 16) | (row << 3).
// (row*8 < 65536 fits the low half and is directly the LDS byte offset.)
__global__ void scatter_kernel(const int* __restrict__ rows, const int* __restrict__ cols,
                               const float* __restrict__ vals,
                               int* __restrict__ cursor, const int* __restrict__ goff,
                               unsigned* __restrict__ ell, int nnz) {
    int i = blockIdx.x * blockDim.x + threadIdx.x;
    if (i < nnz) {
        int c = cols[i];
        int g = c >> 6, lane = c & 63;
        unsigned vb = f32_to_bf16_bits_rne(vals[i]);
        unsigned pk = (vb << 16) | ((unsigned)rows[i] << 3);
        int s = atomicAdd(&cursor[c], 1);
        int idx = goff[g] + ((s >> 2) << 8) + (lane << 2) + (s & 3);
        ell[idx] = pk;
    }
}

__device__ __forceinline__ void process_entry(unsigned pk, const char* xbase,
                                              float& a0, float& a1, float& a2, float& a3) {
    float val = bf16_hi_bits_to_f32(pk);
    unsigned off = pk & 0xFFF8u;            // row*8, padding entries hit row 0 with val 0
    unsigned long long d = *(const unsigned long long*)(xbase + off);
    unsigned lo = (unsigned)d;
    unsigned hi = (unsigned)(d >> 32);
    a0 += val * bf16_lo_bits_to_f32(lo);
    a1 += val * bf16_hi_bits_to_f32(lo);
    a2 += val * bf16_lo_bits_to_f32(hi);
    a3 += val * bf16_hi_bits_to_f32(hi);
}

// Main SpMM: WG = (batch tile of 4) x (half the columns). 8 waves x 8 groups.
__global__ __launch_bounds__(MAIN_THREADS) void spmm_kernel(
        const float* __restrict__ x,
        const float* __restrict__ bias,
        const int* __restrict__ goff,
        const unsigned* __restrict__ ell,
        float* __restrict__ out) {
    __shared__ unsigned long long xl[IN_F];  // 64 KB; 2 WG/CU -> 16 waves/CU
    int w = blockIdx.x;
    int bt = w >> 1;
    int half = w & 1;
    int t = threadIdx.x;
    int b0 = bt * BT;

    for (int r = t; r < IN_F; r += MAIN_THREADS) {
        unsigned u0 = f32_to_bf16_bits_rne(x[(b0 + 0) * IN_F + r]);
        unsigned u1 = f32_to_bf16_bits_rne(x[(b0 + 1) * IN_F + r]);
        unsigned u2 = f32_to_bf16_bits_rne(x[(b0 + 2) * IN_F + r]);
        unsigned u3 = f32_to_bf16_bits_rne(x[(b0 + 3) * IN_F + r]);
        unsigned lo = (u1 << 16) | u0;
        unsigned hi = (u3 << 16) | u2;
        xl[r] = ((unsigned long long)hi << 32) | lo;
    }
    __syncthreads();

    const char* xbase = (const char*)xl;
    int wave = t >> 6;
    int lane = t & 63;

#pragma unroll 1
    for (int it = 0; it < GROUPS_PER_WAVE; ++it) {
        int g = half * 64 + wave * GROUPS_PER_WAVE + it;
        int base = goff[g];
        int n4 = (goff[g + 1] - base) >> 8;       // uint4 iterations (= L_g/4), >=1 in practice
        const uint4* ep = (const uint4*)(ell + base);
        int col = (g << 6) + lane;
        float a0 = 0.f, a1 = 0.f, a2 = 0.f, a3 = 0.f;
        if (n4 > 0) {
            uint4 q = ep[lane];
#pragma unroll 1
            for (int s4 = 1; s4 < n4; ++s4) {
                uint4 qn = ep[s4 * 64 + lane];     // prefetch next (independent of q)
                process_entry(q.x, xbase, a0, a1, a2, a3);
                process_entry(q.y, xbase, a0, a1, a2, a3);
                process_entry(q.z, xbase, a0, a1, a2, a3);
                process_entry(q.w, xbase, a0, a1, a2, a3);
                q = qn;
            }
            process_entry(q.x, xbase, a0, a1, a2, a3);
            process_entry(q.y, xbase, a0, a1, a2, a3);
            process_entry(q.z, xbase, a0, a1, a2, a3);
            process_entry(q.w, xbase, a0, a1, a2, a3);
        }
        float bv = bias[col];
        out[(size_t)(b0 + 0) * OUT_F + col] = a0 + bv;
        out[(size_t)(b0 + 1) * OUT_F + col] = a1 + bv;
        out[(size_t)(b0 + 2) * OUT_F + col] = a2 + bv;
        out[(size_t)(b0 + 3) * OUT_F + col] = a3 + bv;
    }
}

extern "C" void kernel_launch(void* const* d_in, const int* in_sizes, int n_in,
                              void* d_out, int out_size, void* d_ws, size_t ws_size,
                              hipStream_t stream) {
    const float* x      = (const float*)d_in[0];
    const float* values = (const float*)d_in[1];
    const float* bias   = (const float*)d_in[2];
    const int* rows = (const int*)d_in[3];
    const int* cols = (const int*)d_in[4];
    float* out = (float*)d_out;
    int nnz = in_sizes[1];

    int* wsi = (int*)d_ws;
    int* counts = wsi + WS_COUNTS;
    int* cursor = wsi + WS_CURSOR;
    int* goff   = wsi + WS_GOFF;
    unsigned* ell = (unsigned*)(wsi + WS_ELL);

    long long avail = (long long)(ws_size / 4) - WS_ELL;
    int zero_dw = (int)((avail < ELL_ZERO_CAP) ? (avail < 0 ? 0 : avail) : ELL_ZERO_CAP);
    int zero_n4 = zero_dw >> 2;

    zero_kernel<<<(16384 + 255) / 256, 256, 0, stream>>>(counts, 16384);  // counts+cursor
    count_kernel<<<(nnz + 255) / 256, 256, 0, stream>>>(cols, counts, nnz);
    group_kernel<<<1, 128, 0, stream>>>(counts, goff);
    zero4_kernel<<<(zero_n4 + 255) / 256, 256, 0, stream>>>((uint4*)ell, zero_n4);
    scatter_kernel<<<(nnz + 255) / 256, 256, 0, stream>>>(rows, cols, values, cursor, goff, ell, nnz);
    spmm_kernel<<<NBT * COL_HALVES, MAIN_THREADS, 0, stream>>>(x, bias, goff, ell, out);
}